// Round 28
// baseline (101.389 us; speedup 1.0000x reference)
//
#include <hip/hip_runtime.h>

#define N_TOK 2048
#define DIM   512
#define NEXP  16
#define HID   2048
#define NSLOT (N_TOK*2)

typedef __attribute__((ext_vector_type(8))) short short8;
typedef __attribute__((ext_vector_type(4))) float floatx4;

__device__ __forceinline__ ushort f2bf(float f) {
    union { float f; unsigned u; } c; c.f = f;
    unsigned u = c.u;
    unsigned r = (u + 0x7fffu + ((u >> 16) & 1u)) >> 16;
    return (ushort)r;
}
__device__ __forceinline__ float bf2f(ushort u) {
    union { unsigned u; float f; } c; c.u = ((unsigned)u) << 16;
    return c.f;
}

__device__ __forceinline__ void gl_lds16(const void* g, void* l) {
    __builtin_amdgcn_global_load_lds(
        (const __attribute__((address_space(1))) unsigned int*)g,
        (__attribute__((address_space(3))) unsigned int*)l, 16, 0, 0);
}

// ------- Router (fused): RMSNorm + logits + top2 softmax. No atomics. -------
__global__ __launch_bounds__(256)
void router_fused(const float* __restrict__ x, const float* __restrict__ w_norm,
                  const float* __restrict__ Wr, const float* __restrict__ br,
                  ushort* __restrict__ xn, int2* __restrict__ rec_e,
                  float2* __restrict__ rec_w)
{
    __shared__ float xs[16][516];
    __shared__ float wrT[16][516];

    const int tid  = threadIdx.x;
    const int wave = tid >> 6, lane = tid & 63;
    const int tblk = blockIdx.x * 16;

#pragma unroll
    for (int k = 0; k < 32; k++) {
        const int idx = tid + k * 256;
        wrT[idx & 15][idx >> 4] = Wr[idx];
    }

    const float4* wnp = (const float4*)w_norm;
    const float4 wa = wnp[lane], wb = wnp[lane + 64];
#pragma unroll
    for (int i = 0; i < 4; i++) {
        const int tl = wave * 4 + i, t = tblk + tl;
        const float4* xp = (const float4*)(x + (size_t)t * DIM);
        const float4 a = xp[lane], b = xp[lane + 64];
        float ss = a.x*a.x + a.y*a.y + a.z*a.z + a.w*a.w
                 + b.x*b.x + b.y*b.y + b.z*b.z + b.w*b.w;
#pragma unroll
        for (int m = 32; m >= 1; m >>= 1) ss += __shfl_xor(ss, m, 64);
        const float rinv = 1.f / sqrtf(ss * (1.f / (float)DIM) + 1e-10f);
        float4 na, nb;
        na.x = a.x * wa.x * rinv; na.y = a.y * wa.y * rinv;
        na.z = a.z * wa.z * rinv; na.w = a.w * wa.w * rinv;
        nb.x = b.x * wb.x * rinv; nb.y = b.y * wb.y * rinv;
        nb.z = b.z * wb.z * rinv; nb.w = b.w * wb.w * rinv;
        *(float4*)&xs[tl][lane * 4]       = na;
        *(float4*)&xs[tl][256 + lane * 4] = nb;
        ushort4 ua, ub;
        ua.x = f2bf(na.x); ua.y = f2bf(na.y); ua.z = f2bf(na.z); ua.w = f2bf(na.w);
        ub.x = f2bf(nb.x); ub.y = f2bf(nb.y); ub.z = f2bf(nb.z); ub.w = f2bf(nb.w);
        ushort4* xo = (ushort4*)(xn + (size_t)t * DIM);
        xo[lane] = ua; xo[lane + 64] = ub;
    }
    __syncthreads();

    const int tl = tid >> 4, e = tid & 15;
    const int t = tblk + tl;
    float acc = 0.f;
#pragma unroll 4
    for (int d = 0; d < DIM; d += 4) {
        const float4 xv = *(const float4*)&xs[tl][d];
        const float4 wv = *(const float4*)&wrT[e][d];
        acc += xv.x * wv.x + xv.y * wv.y + xv.z * wv.z + xv.w * wv.w;
    }
    const float v = acc + br[e];

    float m0 = v; int i0 = e; float m1 = -1e30f; int i1 = 16;
#pragma unroll
    for (int msk = 1; msk < 16; msk <<= 1) {
        const float om0 = __shfl_xor(m0, msk, 64); const int oi0 = __shfl_xor(i0, msk, 64);
        const float om1 = __shfl_xor(m1, msk, 64); const int oi1 = __shfl_xor(i1, msk, 64);
        const bool bf_ = (om0 > m0) || (om0 == m0 && oi0 < i0);
        const float t0m = bf_ ? om0 : m0; const int t0i = bf_ ? oi0 : i0;
        const float l0m = bf_ ? m0 : om0; const int l0i = bf_ ? i0 : oi0;
        const bool b2_ = (om1 > m1) || (om1 == m1 && oi1 < i1);
        const float t2m = b2_ ? om1 : m1; const int t2i = b2_ ? oi1 : i1;
        const bool lw = (l0m > t2m) || (l0m == t2m && l0i < t2i);
        m0 = t0m; i0 = t0i;
        m1 = lw ? l0m : t2m; i1 = lw ? l0i : t2i;
    }
    if (e == 0) {
        const float ex = expf(m1 - m0);
        const float w0 = 1.f / (1.f + ex);
        rec_e[t] = make_int2(i0, i1);
        rec_w[t] = make_float2(w0, ex * w0);
    }
}

// ------- Plan: counts, offsets, deterministic token-order ranks. 1 block. -------
__global__ __launch_bounds__(1024)
void plan_kernel(const int2* __restrict__ rec_e, int* __restrict__ cnt,
                 int* __restrict__ off, int* __restrict__ tok_of_slot,
                 int* __restrict__ rec_slot)
{
    __shared__ int soff[17];
    const int e = threadIdx.x >> 6;
    const int lane = threadIdx.x & 63;

    int total = 0;
    for (int c = 0; c < N_TOK / 64; c++) {
        const int2 er = rec_e[c * 64 + lane];
        const bool hit = (er.x == e) || (er.y == e);
        total += __popcll(__ballot(hit));
    }
    if (lane == 0) soff[e + 1] = total;
    __syncthreads();
    if (threadIdx.x == 0) {
        soff[0] = 0;
        for (int q = 1; q <= 16; q++) soff[q] += soff[q - 1];
    }
    __syncthreads();
    int base = soff[e];
    if (lane == 0) { cnt[e] = soff[e + 1] - base; off[e] = base; }

    for (int c = 0; c < N_TOK / 64; c++) {
        const int t = c * 64 + lane;
        const int2 er = rec_e[t];
        const bool hit = (er.x == e) || (er.y == e);
        const unsigned long long b = __ballot(hit);
        if (hit) {
            const int slot = base + __popcll(b & ((1ull << lane) - 1ull));
            tok_of_slot[slot] = t;
            const int which = (er.y == e) ? 1 : 0;
            rec_slot[t * 2 + which] = slot;
        }
        base += __popcll(b);
    }
}

// packed bf16 convert: 4x v_cvt_pk_bf16_f32 replaces 8 manual f2bf (~32 VALU)
#define PACK_B_TO(dstptr)                                                    \
    do {                                                                     \
        unsigned pk0, pk1, pk2, pk3;                                         \
        asm("v_cvt_pk_bf16_f32 %0, %1, %2" : "=v"(pk0) : "v"(breg[0]), "v"(breg[1])); \
        asm("v_cvt_pk_bf16_f32 %0, %1, %2" : "=v"(pk1) : "v"(breg[2]), "v"(breg[3])); \
        asm("v_cvt_pk_bf16_f32 %0, %1, %2" : "=v"(pk2) : "v"(breg[4]), "v"(breg[5])); \
        asm("v_cvt_pk_bf16_f32 %0, %1, %2" : "=v"(pk3) : "v"(breg[6]), "v"(breg[7])); \
        *(uint4*)(dstptr) = make_uint4(pk0, pk1, pk2, pk3);                  \
    } while (0)

// ------- GEMM1: reg-staged f32->bf16 B from W1 [e][512][2048]. xcd=e&7. -------
__global__ __launch_bounds__(256)
void gemm1_kernel(const ushort* __restrict__ A,
                  const float* __restrict__ W1, const float* __restrict__ b1,
                  const int* __restrict__ cnt, const int* __restrict__ off,
                  const int* __restrict__ tok_of_slot,
                  ushort* __restrict__ hout)
{
    const int flat = blockIdx.x + (blockIdx.y << 5);   // 0..2047
    const int x = flat & 7;
    const int g = flat >> 3;
    const int e  = x + ((g >> 7) << 3);          // 2 experts per XCD
    const int r0_ = g & 127;
    const int nb = r0_ & 31, mt = r0_ >> 5;      // nb-minor (A-tile reuse)

    const int count = cnt[e];
    if (mt * 128 >= count) return;
    const int base = off[e];
    const int rows = min(128, count - mt * 128);
    const int n0   = nb * 64;

    __shared__ __align__(16) ushort As_[2 * 4096];
    __shared__ __align__(16) ushort Bs_[2 * 2048];
    __shared__ int toks[128];

    const int tid = threadIdx.x;
    if (tid < 128) {
        const int r = tid < rows ? tid : rows - 1;
        toks[tid] = tok_of_slot[base + mt * 128 + r];
    }
    __syncthreads();

    const int lane = tid & 63;
    const int wid  = tid >> 6;
    const int wm = wid >> 1, wn = wid & 1;
    const int fr = lane & 15, fg = lane >> 4;

    const int rl  = lane >> 2;
    const int sko = ((lane & 3) ^ ((lane >> 4) & 3)) * 8;

    const ushort* aptr[2];
#pragma unroll
    for (int j = 0; j < 2; j++) {
        const int s = wid * 2 + j;
        aptr[j] = A + (size_t)toks[s * 16 + rl] * DIM + sko;
    }
    const float* bsrc = W1 + ((size_t)e * DIM + wid * 8) * HID + n0 + lane;
    const int bwoff = lane * 32 + ((wid ^ ((lane >> 1) & 3)) * 8);

    float breg[8];
#define LOADB(ktn)                                                           \
    do {                                                                     \
        _Pragma("unroll")                                                    \
        for (int j = 0; j < 8; j++)                                          \
            breg[j] = bsrc[((size_t)(ktn) * 32 + j) * HID];                  \
    } while (0)
#define WRITEB(pb) PACK_B_TO(&Bs_[(pb) * 2048 + bwoff])
#define STAGEA(pb, k0)                                                       \
    do {                                                                     \
        _Pragma("unroll")                                                    \
        for (int j = 0; j < 2; j++)                                          \
            gl_lds16(aptr[j] + (k0), (void*)(&As_[(pb) * 4096 + (wid * 2 + j) * 512])); \
    } while (0)

    floatx4 acc[4][2];
#pragma unroll
    for (int mi = 0; mi < 4; mi++)
#pragma unroll
        for (int ni = 0; ni < 2; ni++)
#pragma unroll
            for (int r = 0; r < 4; r++) acc[mi][ni][r] = 0.f;

    STAGEA(0, 0);
    LOADB(0);
    asm volatile("s_waitcnt vmcnt(0)" ::: "memory");
    WRITEB(0);

    int cur = 0;
    const int cxor = (fr >> 2) & 3;
    const int cxb  = (fr >> 1) & 3;
    for (int kt = 0; kt < 16; kt++) {
        if (kt < 15) {
            LOADB(kt + 1);
            STAGEA(cur ^ 1, (kt + 1) * 32);
            asm volatile("s_waitcnt vmcnt(10) lgkmcnt(0)" ::: "memory");
        } else {
            asm volatile("s_waitcnt vmcnt(0) lgkmcnt(0)" ::: "memory");
        }
        __builtin_amdgcn_s_barrier();
        __builtin_amdgcn_sched_barrier(0);

        __builtin_amdgcn_s_setprio(1);
        {
            const int co = (fg ^ cxor) * 8;
            const int cob = (fg ^ cxb) * 8;
            short8 af[4], bfr[2];
#pragma unroll
            for (int mi = 0; mi < 4; mi++)
                af[mi] = *(const short8*)&As_[cur * 4096 + (wm * 64 + mi * 16 + fr) * 32 + co];
#pragma unroll
            for (int ni = 0; ni < 2; ni++)
                bfr[ni] = *(const short8*)&Bs_[cur * 2048 + (wn * 32 + ni * 16 + fr) * 32 + cob];
#pragma unroll
            for (int mi = 0; mi < 4; mi++)
#pragma unroll
                for (int ni = 0; ni < 2; ni++)
                    acc[mi][ni] = __builtin_amdgcn_mfma_f32_16x16x32_bf16(af[mi], bfr[ni], acc[mi][ni], 0, 0, 0);
        }
        __builtin_amdgcn_s_setprio(0);

        __builtin_amdgcn_sched_barrier(0);
        __builtin_amdgcn_s_barrier();

        if (kt < 15) {
            asm volatile("s_waitcnt vmcnt(2)" ::: "memory");
            WRITEB(cur ^ 1);
        }
        cur ^= 1;
    }
#undef LOADB
#undef WRITEB
#undef STAGEA

#pragma unroll
    for (int ni = 0; ni < 2; ni++) {
        const int gn = n0 + wn * 32 + ni * 16 + fr;
        const float bv = b1[e * HID + gn];
#pragma unroll
        for (int mi = 0; mi < 4; mi++) {
#pragma unroll
            for (int r = 0; r < 4; r++) {
                const int lm = wm * 64 + mi * 16 + fg * 4 + r;
                if (lm < rows) {
                    const int slot = base + mt * 128 + lm;
                    float v = acc[mi][ni][r] + bv;
                    v = v / (1.f + __expf(-v));
                    hout[(size_t)slot * HID + gn] = f2bf(v);
                }
            }
        }
    }
}

// ------- GEMM2: reg-staged f32->bf16 B from W2 [e][2048][512], split-K=4. ----
// mt-minor ordering: the 4 mt-blocks sharing a 128KB W2 B-panel are
// grid-adjacent -> panel fetched from L3 once (W2 traffic 256->64MB);
// A h-chunks (256KB per (e,z)) stay L2-resident across nb groups.
__global__ __launch_bounds__(256)
void gemm2_kernel(const ushort* __restrict__ A,
                  const float* __restrict__ W2,
                  const int* __restrict__ cnt, const int* __restrict__ off,
                  ushort* __restrict__ yout)
{
    const int flat = blockIdx.x + (blockIdx.y << 5);   // grid 32 x 64 = 2048
    const int x = flat & 7;
    const int g = flat >> 3;
    const int G = ((g >> 5) << 3) + x;   // group 0..63 = e*4+z
    const int e = G >> 2, z = G & 3;
    const int idx = g & 31;
    const int nb = idx >> 2, mt = idx & 3;   // mt-minor (B-panel reuse)

    const int count = cnt[e];
    if (mt * 128 >= count) return;
    const int base = off[e];
    const int rows = min(128, count - mt * 128);
    const int n0   = nb * 64;
    const int kbeg = z * 512;
    ushort* yp = yout + (size_t)z * NSLOT * DIM;

    __shared__ __align__(16) ushort As_[2 * 4096];
    __shared__ __align__(16) ushort Bs_[2 * 2048];
    __shared__ int toks[128];

    const int tid = threadIdx.x;
    if (tid < 128) {
        const int r = tid < rows ? tid : rows - 1;
        toks[tid] = base + mt * 128 + r;
    }
    __syncthreads();

    const int lane = tid & 63;
    const int wid  = tid >> 6;
    const int wm = wid >> 1, wn = wid & 1;
    const int fr = lane & 15, fg = lane >> 4;

    const int rl  = lane >> 2;
    const int sko = ((lane & 3) ^ ((lane >> 4) & 3)) * 8;

    const ushort* aptr[2];
#pragma unroll
    for (int j = 0; j < 2; j++) {
        const int s = wid * 2 + j;
        aptr[j] = A + (size_t)toks[s * 16 + rl] * HID + kbeg + sko;
    }
    const float* bsrc = W2 + ((size_t)e * HID + kbeg + wid * 8) * DIM + n0 + lane;
    const int bwoff = lane * 32 + ((wid ^ ((lane >> 1) & 3)) * 8);

    float breg[8];
#define LOADB(ktn)                                                           \
    do {                                                                     \
        _Pragma("unroll")                                                    \
        for (int j = 0; j < 8; j++)                                          \
            breg[j] = bsrc[((size_t)(ktn) * 32 + j) * DIM];                  \
    } while (0)
#define WRITEB(pb) PACK_B_TO(&Bs_[(pb) * 2048 + bwoff])
#define STAGEA(pb, k0)                                                       \
    do {                                                                     \
        _Pragma("unroll")                                                    \
        for (int j = 0; j < 2; j++)                                          \
            gl_lds16(aptr[j] + (k0), (void*)(&As_[(pb) * 4096 + (wid * 2 + j) * 512])); \
    } while (0)

    floatx4 acc[4][2];
#pragma unroll
    for (int mi = 0; mi < 4; mi++)
#pragma unroll
        for (int ni = 0; ni < 2; ni++)
#pragma unroll
            for (int r = 0; r < 4; r++) acc[mi][ni][r] = 0.f;

    STAGEA(0, 0);
    LOADB(0);
    asm volatile("s_waitcnt vmcnt(0)" ::: "memory");
    WRITEB(0);

    int cur = 0;
    const int cxor = (fr >> 2) & 3;
    const int cxb  = (fr >> 1) & 3;
    for (int kt = 0; kt < 16; kt++) {
        if (kt < 15) {
            LOADB(kt + 1);
            STAGEA(cur ^ 1, (kt + 1) * 32);
            asm volatile("s_waitcnt vmcnt(10) lgkmcnt(0)" ::: "memory");
        } else {
            asm volatile("s_waitcnt vmcnt(0) lgkmcnt(0)" ::: "memory");
        }
        __builtin_amdgcn_s_barrier();
        __builtin_amdgcn_sched_barrier(0);

        __builtin_amdgcn_s_setprio(1);
        {
            const int co = (fg ^ cxor) * 8;
            const int cob = (fg ^ cxb) * 8;
            short8 af[4], bfr[2];
#pragma unroll
            for (int mi = 0; mi < 4; mi++)
                af[mi] = *(const short8*)&As_[cur * 4096 + (wm * 64 + mi * 16 + fr) * 32 + co];
#pragma unroll
            for (int ni = 0; ni < 2; ni++)
                bfr[ni] = *(const short8*)&Bs_[cur * 2048 + (wn * 32 + ni * 16 + fr) * 32 + cob];
#pragma unroll
            for (int mi = 0; mi < 4; mi++)
#pragma unroll
                for (int ni = 0; ni < 2; ni++)
                    acc[mi][ni] = __builtin_amdgcn_mfma_f32_16x16x32_bf16(af[mi], bfr[ni], acc[mi][ni], 0, 0, 0);
        }
        __builtin_amdgcn_s_setprio(0);

        __builtin_amdgcn_sched_barrier(0);
        __builtin_amdgcn_s_barrier();

        if (kt < 15) {
            asm volatile("s_waitcnt vmcnt(2)" ::: "memory");
            WRITEB(cur ^ 1);
        }
        cur ^= 1;
    }
#undef LOADB
#undef WRITEB
#undef STAGEA

#pragma unroll
    for (int ni = 0; ni < 2; ni++) {
        const int gn = n0 + wn * 32 + ni * 16 + fr;
#pragma unroll
        for (int mi = 0; mi < 4; mi++) {
#pragma unroll
            for (int r = 0; r < 4; r++) {
                const int lm = wm * 64 + mi * 16 + fg * 4 + r;
                if (lm < rows) {
                    const int slot = base + mt * 128 + lm;
                    yp[(size_t)slot * DIM + gn] = f2bf(acc[mi][ni][r]);
                }
            }
        }
    }
}

// ------- Gather: out = x + w0*(sum_kc y0 + b2[e0]) + w1*(sum_kc y1 + b2[e1]) -------
__global__ __launch_bounds__(128)
void gather_kernel(const float* __restrict__ x, const ushort* __restrict__ ypart,
                   const float* __restrict__ b2,
                   const int2* __restrict__ rec_e, const float2* __restrict__ rec_w,
                   const int2* __restrict__ rec_slot, float* __restrict__ out)
{
    const int t = blockIdx.x;
    const int d4 = threadIdx.x * 4;
    const int2 ei = rec_e[t];
    const float2 w = rec_w[t];
    const int2 sl = rec_slot[t];
    const float4 xv  = *(const float4*)(x  + (size_t)t * DIM + d4);
    float4 s0 = make_float4(0.f, 0.f, 0.f, 0.f);
    float4 s1 = make_float4(0.f, 0.f, 0.f, 0.f);
#pragma unroll
    for (int kc = 0; kc < 4; kc++) {
        const ushort* yp = ypart + (size_t)kc * NSLOT * DIM;
        const ushort4 a = *(const ushort4*)(yp + (size_t)sl.x * DIM + d4);
        const ushort4 b = *(const ushort4*)(yp + (size_t)sl.y * DIM + d4);
        s0.x += bf2f(a.x); s0.y += bf2f(a.y); s0.z += bf2f(a.z); s0.w += bf2f(a.w);
        s1.x += bf2f(b.x); s1.y += bf2f(b.y); s1.z += bf2f(b.z); s1.w += bf2f(b.w);
    }
    const float4 b0  = *(const float4*)(b2 + (size_t)ei.x * DIM + d4);
    const float4 b1v = *(const float4*)(b2 + (size_t)ei.y * DIM + d4);
    float4 o;
    o.x = xv.x + w.x * (s0.x + b0.x) + w.y * (s1.x + b1v.x);
    o.y = xv.y + w.x * (s0.y + b0.y) + w.y * (s1.y + b1v.y);
    o.z = xv.z + w.x * (s0.z + b0.z) + w.y * (s1.z + b1v.z);
    o.w = xv.w + w.x * (s0.w + b0.w) + w.y * (s1.w + b1v.w);
    *(float4*)(out + (size_t)t * DIM + d4) = o;
}

extern "C" void kernel_launch(void* const* d_in, const int* in_sizes, int n_in,
                              void* d_out, int out_size, void* d_ws, size_t ws_size,
                              hipStream_t stream)
{
    const float* x  = (const float*)d_in[0];
    const float* wn = (const float*)d_in[1];
    const float* Wr = (const float*)d_in[2];
    const float* br = (const float*)d_in[3];
    const float* W1 = (const float*)d_in[4];
    const float* b1 = (const float*)d_in[5];
    const float* W2 = (const float*)d_in[6];
    const float* b2 = (const float*)d_in[7];
    float* out = (float*)d_out;

    char* ws = (char*)d_ws;
    ushort* xn    = (ushort*)(ws);                  // 2 MB
    ushort* h_buf = (ushort*)(ws + (2u  << 20));    // 16 MB
    ushort* y_par = (ushort*)(ws + (18u << 20));    // 16 MB (4 x 4 MB bf16 partials)
    char* p = ws + (40u << 20);
    int*    cnt         = (int*)p;    p += 256;
    int*    off         = (int*)p;    p += 256;
    int2*   rec_e       = (int2*)p;   p += N_TOK * 8;
    float2* rec_w       = (float2*)p; p += N_TOK * 8;
    int2*   rec_slot    = (int2*)p;   p += N_TOK * 8;
    int*    tok_of_slot = (int*)p;    p += NSLOT * 4;

    // A: router
    router_fused<<<N_TOK / 16, 256, 0, stream>>>(x, wn, Wr, br, xn, rec_e, rec_w);

    // B: plan
    plan_kernel<<<1, 1024, 0, stream>>>(rec_e, cnt, off, tok_of_slot, (int*)rec_slot);

    // C: GEMM1 (reg-staged f32->bf16 B from W1, packed cvt, nb-minor)
    gemm1_kernel<<<dim3(32, 64), 256, 0, stream>>>(
        xn, W1, b1, cnt, off, tok_of_slot, h_buf);

    // D: GEMM2 (reg-staged f32->bf16 B from W2, split-K=4, packed cvt, mt-minor)
    gemm2_kernel<<<dim3(32, 64), 256, 0, stream>>>(h_buf, W2, cnt, off, y_par);

    // E: gather
    gather_kernel<<<N_TOK, 128, 0, stream>>>(x, y_par, b2, rec_e, rec_w, rec_slot, out);
}

// Round 29
// 95.860 us; speedup vs baseline: 1.0577x; 1.0577x over previous
//
#include <hip/hip_runtime.h>

#define N_TOK 2048
#define DIM   512
#define NEXP  16
#define HID   2048
#define NSLOT (N_TOK*2)

typedef __attribute__((ext_vector_type(8))) short short8;
typedef __attribute__((ext_vector_type(4))) float floatx4;

__device__ __forceinline__ ushort f2bf(float f) {
    union { float f; unsigned u; } c; c.f = f;
    unsigned u = c.u;
    unsigned r = (u + 0x7fffu + ((u >> 16) & 1u)) >> 16;
    return (ushort)r;
}
__device__ __forceinline__ float bf2f(ushort u) {
    union { unsigned u; float f; } c; c.u = ((unsigned)u) << 16;
    return c.f;
}

__device__ __forceinline__ void gl_lds16(const void* g, void* l) {
    __builtin_amdgcn_global_load_lds(
        (const __attribute__((address_space(1))) unsigned int*)g,
        (__attribute__((address_space(3))) unsigned int*)l, 16, 0, 0);
}

// ------- Router (fused): RMSNorm + logits + top2 softmax. No atomics. -------
__global__ __launch_bounds__(256)
void router_fused(const float* __restrict__ x, const float* __restrict__ w_norm,
                  const float* __restrict__ Wr, const float* __restrict__ br,
                  ushort* __restrict__ xn, int2* __restrict__ rec_e,
                  float2* __restrict__ rec_w)
{
    __shared__ float xs[16][516];
    __shared__ float wrT[16][516];

    const int tid  = threadIdx.x;
    const int wave = tid >> 6, lane = tid & 63;
    const int tblk = blockIdx.x * 16;

#pragma unroll
    for (int k = 0; k < 32; k++) {
        const int idx = tid + k * 256;
        wrT[idx & 15][idx >> 4] = Wr[idx];
    }

    const float4* wnp = (const float4*)w_norm;
    const float4 wa = wnp[lane], wb = wnp[lane + 64];
#pragma unroll
    for (int i = 0; i < 4; i++) {
        const int tl = wave * 4 + i, t = tblk + tl;
        const float4* xp = (const float4*)(x + (size_t)t * DIM);
        const float4 a = xp[lane], b = xp[lane + 64];
        float ss = a.x*a.x + a.y*a.y + a.z*a.z + a.w*a.w
                 + b.x*b.x + b.y*b.y + b.z*b.z + b.w*b.w;
#pragma unroll
        for (int m = 32; m >= 1; m >>= 1) ss += __shfl_xor(ss, m, 64);
        const float rinv = 1.f / sqrtf(ss * (1.f / (float)DIM) + 1e-10f);
        float4 na, nb;
        na.x = a.x * wa.x * rinv; na.y = a.y * wa.y * rinv;
        na.z = a.z * wa.z * rinv; na.w = a.w * wa.w * rinv;
        nb.x = b.x * wb.x * rinv; nb.y = b.y * wb.y * rinv;
        nb.z = b.z * wb.z * rinv; nb.w = b.w * wb.w * rinv;
        *(float4*)&xs[tl][lane * 4]       = na;
        *(float4*)&xs[tl][256 + lane * 4] = nb;
        ushort4 ua, ub;
        ua.x = f2bf(na.x); ua.y = f2bf(na.y); ua.z = f2bf(na.z); ua.w = f2bf(na.w);
        ub.x = f2bf(nb.x); ub.y = f2bf(nb.y); ub.z = f2bf(nb.z); ub.w = f2bf(nb.w);
        ushort4* xo = (ushort4*)(xn + (size_t)t * DIM);
        xo[lane] = ua; xo[lane + 64] = ub;
    }
    __syncthreads();

    const int tl = tid >> 4, e = tid & 15;
    const int t = tblk + tl;
    float acc = 0.f;
#pragma unroll 4
    for (int d = 0; d < DIM; d += 4) {
        const float4 xv = *(const float4*)&xs[tl][d];
        const float4 wv = *(const float4*)&wrT[e][d];
        acc += xv.x * wv.x + xv.y * wv.y + xv.z * wv.z + xv.w * wv.w;
    }
    const float v = acc + br[e];

    float m0 = v; int i0 = e; float m1 = -1e30f; int i1 = 16;
#pragma unroll
    for (int msk = 1; msk < 16; msk <<= 1) {
        const float om0 = __shfl_xor(m0, msk, 64); const int oi0 = __shfl_xor(i0, msk, 64);
        const float om1 = __shfl_xor(m1, msk, 64); const int oi1 = __shfl_xor(i1, msk, 64);
        const bool bf_ = (om0 > m0) || (om0 == m0 && oi0 < i0);
        const float t0m = bf_ ? om0 : m0; const int t0i = bf_ ? oi0 : i0;
        const float l0m = bf_ ? m0 : om0; const int l0i = bf_ ? i0 : oi0;
        const bool b2_ = (om1 > m1) || (om1 == m1 && oi1 < i1);
        const float t2m = b2_ ? om1 : m1; const int t2i = b2_ ? oi1 : i1;
        const bool lw = (l0m > t2m) || (l0m == t2m && l0i < t2i);
        m0 = t0m; i0 = t0i;
        m1 = lw ? l0m : t2m; i1 = lw ? l0i : t2i;
    }
    if (e == 0) {
        const float ex = expf(m1 - m0);
        const float w0 = 1.f / (1.f + ex);
        rec_e[t] = make_int2(i0, i1);
        rec_w[t] = make_float2(w0, ex * w0);
    }
}

// ------- Plan: counts, offsets, deterministic token-order ranks. 1 block. -------
__global__ __launch_bounds__(1024)
void plan_kernel(const int2* __restrict__ rec_e, int* __restrict__ cnt,
                 int* __restrict__ off, int* __restrict__ tok_of_slot,
                 int* __restrict__ rec_slot)
{
    __shared__ int soff[17];
    const int e = threadIdx.x >> 6;
    const int lane = threadIdx.x & 63;

    int total = 0;
    for (int c = 0; c < N_TOK / 64; c++) {
        const int2 er = rec_e[c * 64 + lane];
        const bool hit = (er.x == e) || (er.y == e);
        total += __popcll(__ballot(hit));
    }
    if (lane == 0) soff[e + 1] = total;
    __syncthreads();
    if (threadIdx.x == 0) {
        soff[0] = 0;
        for (int q = 1; q <= 16; q++) soff[q] += soff[q - 1];
    }
    __syncthreads();
    int base = soff[e];
    if (lane == 0) { cnt[e] = soff[e + 1] - base; off[e] = base; }

    for (int c = 0; c < N_TOK / 64; c++) {
        const int t = c * 64 + lane;
        const int2 er = rec_e[t];
        const bool hit = (er.x == e) || (er.y == e);
        const unsigned long long b = __ballot(hit);
        if (hit) {
            const int slot = base + __popcll(b & ((1ull << lane) - 1ull));
            tok_of_slot[slot] = t;
            const int which = (er.y == e) ? 1 : 0;
            rec_slot[t * 2 + which] = slot;
        }
        base += __popcll(b);
    }
}

// packed bf16 convert: 4x v_cvt_pk_bf16_f32 replaces 8 manual f2bf (~32 VALU)
#define PACK_B_TO(dstptr)                                                    \
    do {                                                                     \
        unsigned pk0, pk1, pk2, pk3;                                         \
        asm("v_cvt_pk_bf16_f32 %0, %1, %2" : "=v"(pk0) : "v"(breg[0]), "v"(breg[1])); \
        asm("v_cvt_pk_bf16_f32 %0, %1, %2" : "=v"(pk1) : "v"(breg[2]), "v"(breg[3])); \
        asm("v_cvt_pk_bf16_f32 %0, %1, %2" : "=v"(pk2) : "v"(breg[4]), "v"(breg[5])); \
        asm("v_cvt_pk_bf16_f32 %0, %1, %2" : "=v"(pk3) : "v"(breg[6]), "v"(breg[7])); \
        *(uint4*)(dstptr) = make_uint4(pk0, pk1, pk2, pk3);                  \
    } while (0)

// ------- GEMM1: reg-staged f32->bf16 B from W1 [e][512][2048]. xcd=e&7. -------
__global__ __launch_bounds__(256)
void gemm1_kernel(const ushort* __restrict__ A,
                  const float* __restrict__ W1, const float* __restrict__ b1,
                  const int* __restrict__ cnt, const int* __restrict__ off,
                  const int* __restrict__ tok_of_slot,
                  ushort* __restrict__ hout)
{
    const int flat = blockIdx.x + (blockIdx.y << 5);   // 0..2047
    const int x = flat & 7;
    const int g = flat >> 3;
    const int e  = x + ((g >> 7) << 3);          // 2 experts per XCD
    const int r0_ = g & 127;
    const int nb = r0_ & 31, mt = r0_ >> 5;      // nb-minor (A-tile reuse)

    const int count = cnt[e];
    if (mt * 128 >= count) return;
    const int base = off[e];
    const int rows = min(128, count - mt * 128);
    const int n0   = nb * 64;

    __shared__ __align__(16) ushort As_[2 * 4096];
    __shared__ __align__(16) ushort Bs_[2 * 2048];
    __shared__ int toks[128];

    const int tid = threadIdx.x;
    if (tid < 128) {
        const int r = tid < rows ? tid : rows - 1;
        toks[tid] = tok_of_slot[base + mt * 128 + r];
    }
    __syncthreads();

    const int lane = tid & 63;
    const int wid  = tid >> 6;
    const int wm = wid >> 1, wn = wid & 1;
    const int fr = lane & 15, fg = lane >> 4;

    const int rl  = lane >> 2;
    const int sko = ((lane & 3) ^ ((lane >> 4) & 3)) * 8;

    const ushort* aptr[2];
#pragma unroll
    for (int j = 0; j < 2; j++) {
        const int s = wid * 2 + j;
        aptr[j] = A + (size_t)toks[s * 16 + rl] * DIM + sko;
    }
    const float* bsrc = W1 + ((size_t)e * DIM + wid * 8) * HID + n0 + lane;
    const int bwoff = lane * 32 + ((wid ^ ((lane >> 1) & 3)) * 8);

    float breg[8];
#define LOADB(ktn)                                                           \
    do {                                                                     \
        _Pragma("unroll")                                                    \
        for (int j = 0; j < 8; j++)                                          \
            breg[j] = bsrc[((size_t)(ktn) * 32 + j) * HID];                  \
    } while (0)
#define WRITEB(pb) PACK_B_TO(&Bs_[(pb) * 2048 + bwoff])
#define STAGEA(pb, k0)                                                       \
    do {                                                                     \
        _Pragma("unroll")                                                    \
        for (int j = 0; j < 2; j++)                                          \
            gl_lds16(aptr[j] + (k0), (void*)(&As_[(pb) * 4096 + (wid * 2 + j) * 512])); \
    } while (0)

    floatx4 acc[4][2];
#pragma unroll
    for (int mi = 0; mi < 4; mi++)
#pragma unroll
        for (int ni = 0; ni < 2; ni++)
#pragma unroll
            for (int r = 0; r < 4; r++) acc[mi][ni][r] = 0.f;

    STAGEA(0, 0);
    LOADB(0);
    asm volatile("s_waitcnt vmcnt(0)" ::: "memory");
    WRITEB(0);

    int cur = 0;
    const int cxor = (fr >> 2) & 3;
    const int cxb  = (fr >> 1) & 3;
    for (int kt = 0; kt < 16; kt++) {
        if (kt < 15) {
            LOADB(kt + 1);
            STAGEA(cur ^ 1, (kt + 1) * 32);
            asm volatile("s_waitcnt vmcnt(10) lgkmcnt(0)" ::: "memory");
        } else {
            asm volatile("s_waitcnt vmcnt(0) lgkmcnt(0)" ::: "memory");
        }
        __builtin_amdgcn_s_barrier();
        __builtin_amdgcn_sched_barrier(0);

        __builtin_amdgcn_s_setprio(1);
        {
            const int co = (fg ^ cxor) * 8;
            const int cob = (fg ^ cxb) * 8;
            short8 af[4], bfr[2];
#pragma unroll
            for (int mi = 0; mi < 4; mi++)
                af[mi] = *(const short8*)&As_[cur * 4096 + (wm * 64 + mi * 16 + fr) * 32 + co];
#pragma unroll
            for (int ni = 0; ni < 2; ni++)
                bfr[ni] = *(const short8*)&Bs_[cur * 2048 + (wn * 32 + ni * 16 + fr) * 32 + cob];
#pragma unroll
            for (int mi = 0; mi < 4; mi++)
#pragma unroll
                for (int ni = 0; ni < 2; ni++)
                    acc[mi][ni] = __builtin_amdgcn_mfma_f32_16x16x32_bf16(af[mi], bfr[ni], acc[mi][ni], 0, 0, 0);
        }
        __builtin_amdgcn_s_setprio(0);

        __builtin_amdgcn_sched_barrier(0);
        __builtin_amdgcn_s_barrier();

        if (kt < 15) {
            asm volatile("s_waitcnt vmcnt(2)" ::: "memory");
            WRITEB(cur ^ 1);
        }
        cur ^= 1;
    }
#undef LOADB
#undef WRITEB
#undef STAGEA

#pragma unroll
    for (int ni = 0; ni < 2; ni++) {
        const int gn = n0 + wn * 32 + ni * 16 + fr;
        const float bv = b1[e * HID + gn];
#pragma unroll
        for (int mi = 0; mi < 4; mi++) {
#pragma unroll
            for (int r = 0; r < 4; r++) {
                const int lm = wm * 64 + mi * 16 + fg * 4 + r;
                if (lm < rows) {
                    const int slot = base + mt * 128 + lm;
                    float v = acc[mi][ni][r] + bv;
                    v = v / (1.f + __expf(-v));
                    hout[(size_t)slot * HID + gn] = f2bf(v);
                }
            }
        }
    }
}

// ------- GEMM2: reg-staged f32->bf16 B from W2 [e][2048][512], split-K=4. ----
__global__ __launch_bounds__(256)
void gemm2_kernel(const ushort* __restrict__ A,
                  const float* __restrict__ W2,
                  const int* __restrict__ cnt, const int* __restrict__ off,
                  ushort* __restrict__ yout)
{
    const int flat = blockIdx.x + (blockIdx.y << 5);   // grid 32 x 64 = 2048
    const int x = flat & 7;
    const int g = flat >> 3;
    const int G = ((g >> 5) << 3) + x;   // group 0..63 = e*4+z
    const int e = G >> 2, z = G & 3;
    const int idx = g & 31;
    const int mt = idx >> 3, nb = idx & 7;   // nb-minor (A-tile reuse)

    const int count = cnt[e];
    if (mt * 128 >= count) return;
    const int base = off[e];
    const int rows = min(128, count - mt * 128);
    const int n0   = nb * 64;
    const int kbeg = z * 512;
    ushort* yp = yout + (size_t)z * NSLOT * DIM;

    __shared__ __align__(16) ushort As_[2 * 4096];
    __shared__ __align__(16) ushort Bs_[2 * 2048];
    __shared__ int toks[128];

    const int tid = threadIdx.x;
    if (tid < 128) {
        const int r = tid < rows ? tid : rows - 1;
        toks[tid] = base + mt * 128 + r;
    }
    __syncthreads();

    const int lane = tid & 63;
    const int wid  = tid >> 6;
    const int wm = wid >> 1, wn = wid & 1;
    const int fr = lane & 15, fg = lane >> 4;

    const int rl  = lane >> 2;
    const int sko = ((lane & 3) ^ ((lane >> 4) & 3)) * 8;

    const ushort* aptr[2];
#pragma unroll
    for (int j = 0; j < 2; j++) {
        const int s = wid * 2 + j;
        aptr[j] = A + (size_t)toks[s * 16 + rl] * HID + kbeg + sko;
    }
    const float* bsrc = W2 + ((size_t)e * HID + kbeg + wid * 8) * DIM + n0 + lane;
    const int bwoff = lane * 32 + ((wid ^ ((lane >> 1) & 3)) * 8);

    float breg[8];
#define LOADB(ktn)                                                           \
    do {                                                                     \
        _Pragma("unroll")                                                    \
        for (int j = 0; j < 8; j++)                                          \
            breg[j] = bsrc[((size_t)(ktn) * 32 + j) * DIM];                  \
    } while (0)
#define WRITEB(pb) PACK_B_TO(&Bs_[(pb) * 2048 + bwoff])
#define STAGEA(pb, k0)                                                       \
    do {                                                                     \
        _Pragma("unroll")                                                    \
        for (int j = 0; j < 2; j++)                                          \
            gl_lds16(aptr[j] + (k0), (void*)(&As_[(pb) * 4096 + (wid * 2 + j) * 512])); \
    } while (0)

    floatx4 acc[4][2];
#pragma unroll
    for (int mi = 0; mi < 4; mi++)
#pragma unroll
        for (int ni = 0; ni < 2; ni++)
#pragma unroll
            for (int r = 0; r < 4; r++) acc[mi][ni][r] = 0.f;

    STAGEA(0, 0);
    LOADB(0);
    asm volatile("s_waitcnt vmcnt(0)" ::: "memory");
    WRITEB(0);

    int cur = 0;
    const int cxor = (fr >> 2) & 3;
    const int cxb  = (fr >> 1) & 3;
    for (int kt = 0; kt < 16; kt++) {
        if (kt < 15) {
            LOADB(kt + 1);
            STAGEA(cur ^ 1, (kt + 1) * 32);
            asm volatile("s_waitcnt vmcnt(10) lgkmcnt(0)" ::: "memory");
        } else {
            asm volatile("s_waitcnt vmcnt(0) lgkmcnt(0)" ::: "memory");
        }
        __builtin_amdgcn_s_barrier();
        __builtin_amdgcn_sched_barrier(0);

        __builtin_amdgcn_s_setprio(1);
        {
            const int co = (fg ^ cxor) * 8;
            const int cob = (fg ^ cxb) * 8;
            short8 af[4], bfr[2];
#pragma unroll
            for (int mi = 0; mi < 4; mi++)
                af[mi] = *(const short8*)&As_[cur * 4096 + (wm * 64 + mi * 16 + fr) * 32 + co];
#pragma unroll
            for (int ni = 0; ni < 2; ni++)
                bfr[ni] = *(const short8*)&Bs_[cur * 2048 + (wn * 32 + ni * 16 + fr) * 32 + cob];
#pragma unroll
            for (int mi = 0; mi < 4; mi++)
#pragma unroll
                for (int ni = 0; ni < 2; ni++)
                    acc[mi][ni] = __builtin_amdgcn_mfma_f32_16x16x32_bf16(af[mi], bfr[ni], acc[mi][ni], 0, 0, 0);
        }
        __builtin_amdgcn_s_setprio(0);

        __builtin_amdgcn_sched_barrier(0);
        __builtin_amdgcn_s_barrier();

        if (kt < 15) {
            asm volatile("s_waitcnt vmcnt(2)" ::: "memory");
            WRITEB(cur ^ 1);
        }
        cur ^= 1;
    }
#undef LOADB
#undef WRITEB
#undef STAGEA

#pragma unroll
    for (int ni = 0; ni < 2; ni++) {
        const int gn = n0 + wn * 32 + ni * 16 + fr;
#pragma unroll
        for (int mi = 0; mi < 4; mi++) {
#pragma unroll
            for (int r = 0; r < 4; r++) {
                const int lm = wm * 64 + mi * 16 + fg * 4 + r;
                if (lm < rows) {
                    const int slot = base + mt * 128 + lm;
                    yp[(size_t)slot * DIM + gn] = f2bf(acc[mi][ni][r]);
                }
            }
        }
    }
}

// ------- Gather: out = x + w0*(sum_kc y0 + b2[e0]) + w1*(sum_kc y1 + b2[e1]) -------
__global__ __launch_bounds__(128)
void gather_kernel(const float* __restrict__ x, const ushort* __restrict__ ypart,
                   const float* __restrict__ b2,
                   const int2* __restrict__ rec_e, const float2* __restrict__ rec_w,
                   const int2* __restrict__ rec_slot, float* __restrict__ out)
{
    const int t = blockIdx.x;
    const int d4 = threadIdx.x * 4;
    const int2 ei = rec_e[t];
    const float2 w = rec_w[t];
    const int2 sl = rec_slot[t];
    const float4 xv  = *(const float4*)(x  + (size_t)t * DIM + d4);
    float4 s0 = make_float4(0.f, 0.f, 0.f, 0.f);
    float4 s1 = make_float4(0.f, 0.f, 0.f, 0.f);
#pragma unroll
    for (int kc = 0; kc < 4; kc++) {
        const ushort* yp = ypart + (size_t)kc * NSLOT * DIM;
        const ushort4 a = *(const ushort4*)(yp + (size_t)sl.x * DIM + d4);
        const ushort4 b = *(const ushort4*)(yp + (size_t)sl.y * DIM + d4);
        s0.x += bf2f(a.x); s0.y += bf2f(a.y); s0.z += bf2f(a.z); s0.w += bf2f(a.w);
        s1.x += bf2f(b.x); s1.y += bf2f(b.y); s1.z += bf2f(b.z); s1.w += bf2f(b.w);
    }
    const float4 b0  = *(const float4*)(b2 + (size_t)ei.x * DIM + d4);
    const float4 b1v = *(const float4*)(b2 + (size_t)ei.y * DIM + d4);
    float4 o;
    o.x = xv.x + w.x * (s0.x + b0.x) + w.y * (s1.x + b1v.x);
    o.y = xv.y + w.x * (s0.y + b0.y) + w.y * (s1.y + b1v.y);
    o.z = xv.z + w.x * (s0.z + b0.z) + w.y * (s1.z + b1v.z);
    o.w = xv.w + w.x * (s0.w + b0.w) + w.y * (s1.w + b1v.w);
    *(float4*)(out + (size_t)t * DIM + d4) = o;
}

extern "C" void kernel_launch(void* const* d_in, const int* in_sizes, int n_in,
                              void* d_out, int out_size, void* d_ws, size_t ws_size,
                              hipStream_t stream)
{
    const float* x  = (const float*)d_in[0];
    const float* wn = (const float*)d_in[1];
    const float* Wr = (const float*)d_in[2];
    const float* br = (const float*)d_in[3];
    const float* W1 = (const float*)d_in[4];
    const float* b1 = (const float*)d_in[5];
    const float* W2 = (const float*)d_in[6];
    const float* b2 = (const float*)d_in[7];
    float* out = (float*)d_out;

    char* ws = (char*)d_ws;
    ushort* xn    = (ushort*)(ws);                  // 2 MB
    ushort* h_buf = (ushort*)(ws + (2u  << 20));    // 16 MB
    ushort* y_par = (ushort*)(ws + (18u << 20));    // 16 MB (4 x 4 MB bf16 partials)
    char* p = ws + (40u << 20);
    int*    cnt         = (int*)p;    p += 256;
    int*    off         = (int*)p;    p += 256;
    int2*   rec_e       = (int2*)p;   p += N_TOK * 8;
    float2* rec_w       = (float2*)p; p += N_TOK * 8;
    int2*   rec_slot    = (int2*)p;   p += N_TOK * 8;
    int*    tok_of_slot = (int*)p;    p += NSLOT * 4;

    // A: router
    router_fused<<<N_TOK / 16, 256, 0, stream>>>(x, wn, Wr, br, xn, rec_e, rec_w);

    // B: plan
    plan_kernel<<<1, 1024, 0, stream>>>(rec_e, cnt, off, tok_of_slot, (int*)rec_slot);

    // C: GEMM1 (reg-staged f32->bf16 B from W1, packed cvt, nb-minor)
    gemm1_kernel<<<dim3(32, 64), 256, 0, stream>>>(
        xn, W1, b1, cnt, off, tok_of_slot, h_buf);

    // D: GEMM2 (reg-staged f32->bf16 B from W2, split-K=4, packed cvt, nb-minor)
    gemm2_kernel<<<dim3(32, 64), 256, 0, stream>>>(h_buf, W2, cnt, off, y_par);

    // E: gather
    gather_kernel<<<N_TOK, 128, 0, stream>>>(x, y_par, b2, rec_e, rec_w, rec_slot, out);
}